// Round 1
// baseline (2846.427 us; speedup 1.0000x reference)
//
#include <hip/hip_runtime.h>
#include <hip/hip_bf16.h>

// Problem constants (fixed by reference)
#define NN 4096      // nodes
#define EE 16384     // edges
#define GG 128       // graphs
#define HH 64        // hidden / in_dim
#define EDIM 16      // edge_dim
#define HD 4096      // edge-MLP width = 64*64

typedef __attribute__((ext_vector_type(8))) short short8;
typedef __attribute__((ext_vector_type(4))) float float4v;

static __device__ inline unsigned short f2b(float f) {
    unsigned u = __float_as_uint(f);
    unsigned r = u + 0x7fff + ((u >> 16) & 1);   // RNE
    return (unsigned short)(r >> 16);
}

// ---------------------------------------------------------------------------
// 1. w2 [HD][HD] fp32  ->  w2t [n][k] bf16 (transposed), LDS-tiled
// ---------------------------------------------------------------------------
__global__ void wcast(const float* __restrict__ w2, unsigned short* __restrict__ w2t) {
    __shared__ float t[64 * 65];
    const int n0 = blockIdx.x * 64;
    const int k0 = blockIdx.y * 64;
    const int tid = threadIdx.x;
    const int cr = tid >> 6;   // 0..3
    const int cc = tid & 63;
#pragma unroll
    for (int it = 0; it < 16; ++it) {
        int kl = it * 4 + cr;
        t[kl * 65 + cc] = w2[(size_t)(k0 + kl) * HD + n0 + cc];
    }
    __syncthreads();
#pragma unroll
    for (int it = 0; it < 16; ++it) {
        int nl = it * 4 + cr;
        w2t[(size_t)(n0 + nl) * HD + k0 + cc] = f2b(t[cc * 65 + nl]);
    }
}

// ---------------------------------------------------------------------------
// 2. h = relu(ea @ w1 + b1) -> bf16 [EE][HD]
//    grid: (HD/256, EE/16), block 256
// ---------------------------------------------------------------------------
__global__ void hker(const float* __restrict__ ea, const float* __restrict__ w1,
                     const float* __restrict__ b1, unsigned short* __restrict__ hB) {
    __shared__ float sea[16 * 16];
    const int tid = threadIdx.x;
    const int j = blockIdx.x * 256 + tid;
    const int e0 = blockIdx.y * 16;
    float w[16];
#pragma unroll
    for (int k = 0; k < 16; ++k) w[k] = w1[k * HD + j];
    const float b = b1[j];
    sea[tid] = ea[e0 * EDIM + tid];
    __syncthreads();
#pragma unroll 4
    for (int el = 0; el < 16; ++el) {
        float a = b;
#pragma unroll
        for (int k = 0; k < 16; ++k) a += sea[el * 16 + k] * w[k];
        hB[(size_t)(e0 + el) * HD + j] = f2b(fmaxf(a, 0.f));
    }
}

// ---------------------------------------------------------------------------
// 3. msg[e,o] = sum_i x[src[e],i] * b2[i*64+o]   (fp32; also zero-inits msg)
// ---------------------------------------------------------------------------
__global__ void msg_init(const float* __restrict__ xcur, const int* __restrict__ src,
                         const float* __restrict__ b2, float* __restrict__ msg) {
    const int e = blockIdx.x * 4 + (threadIdx.x >> 6);
    const int o = threadIdx.x & 63;
    const int s = src[e];
    float a = 0.f;
#pragma unroll
    for (int i = 0; i < 64; ++i) a += xcur[s * 64 + i] * b2[i * 64 + o];
    msg[e * 64 + o] = a;
}

// ---------------------------------------------------------------------------
// 4. The big fused GEMM: for edges tile [128] x col group [512]:
//    D = (h @ w2) tile, contracted on the fly:  msg[e,o] += x_s[e,i]*D[e, i*64+o]
//    grid (EE/128, HD/512), block 256 (4 waves, 2x2)
// ---------------------------------------------------------------------------
#define BM 128
#define BK 32
#define LDK 40   // padded LDS k-stride (80 B, multiple of 16 B)

__global__ __launch_bounds__(256, 2)
void gemm_msg(const unsigned short* __restrict__ hB, const unsigned short* __restrict__ w2t,
              const float* __restrict__ xcur, const int* __restrict__ src,
              float* __restrict__ msg) {
    __shared__ __align__(16) unsigned short As[BM * LDK];
    __shared__ __align__(16) unsigned short Bs[128 * LDK];
    __shared__ float lds_msg[BM * 64];
    __shared__ float lds_xs[BM * 8];

    const int tid = threadIdx.x;
    const int bx = blockIdx.x;          // edge tile
    const int by = blockIdx.y;          // 512-col group
    const int e0 = bx * BM;
    const int ibase = by * 8;

    // stage x[src[e], ibase..ibase+7]
#pragma unroll
    for (int it = 0; it < 4; ++it) {
        int idx = it * 256 + tid;       // 0..1023
        int r = idx >> 3, ii = idx & 7;
        int sn = src[e0 + r];
        lds_xs[r * 8 + ii] = xcur[sn * 64 + ibase + ii];
    }
#pragma unroll
    for (int it = 0; it < 32; ++it) lds_msg[it * 256 + tid] = 0.f;
    __syncthreads();

    const int lane = tid & 63;
    const int wave = tid >> 6;
    const int quad = lane >> 4;
    const int lm = lane & 15;
    const int wm = wave >> 1;           // row half
    const int wn = wave & 1;            // col half

    const int sr = tid >> 2;            // 0..63 staging row
    const int sc = (tid & 3) * 8;       // 0,8,16,24 staging col (bf16 elems)

    for (int ct = 0; ct < 4; ++ct) {
        const int n0 = by * 512 + ct * 128;   // global col base
        float4v acc[4][4];
#pragma unroll
        for (int s = 0; s < 4; ++s)
#pragma unroll
            for (int t = 0; t < 4; ++t) {
                acc[s][t][0] = 0.f; acc[s][t][1] = 0.f;
                acc[s][t][2] = 0.f; acc[s][t][3] = 0.f;
            }

        for (int ks = 0; ks < HD / BK; ++ks) {
            const int k0 = ks * BK;
            // stage A (128x32) and B (128 cols x 32 k), 16B per lane, 2 rows each
            {
                const unsigned short* gA = hB + (size_t)(e0 + sr) * HD + k0 + sc;
                *(uint4*)(&As[sr * LDK + sc]) = *(const uint4*)gA;
                *(uint4*)(&As[(sr + 64) * LDK + sc]) = *(const uint4*)(gA + (size_t)64 * HD);
                const unsigned short* gB = w2t + (size_t)(n0 + sr) * HD + k0 + sc;
                *(uint4*)(&Bs[sr * LDK + sc]) = *(const uint4*)gB;
                *(uint4*)(&Bs[(sr + 64) * LDK + sc]) = *(const uint4*)(gB + (size_t)64 * HD);
            }
            __syncthreads();
            short8 af[4], bf[4];
#pragma unroll
            for (int s = 0; s < 4; ++s)
                af[s] = *(const short8*)(&As[(wm * 64 + s * 16 + lm) * LDK + quad * 8]);
#pragma unroll
            for (int t = 0; t < 4; ++t)
                bf[t] = *(const short8*)(&Bs[(wn * 64 + t * 16 + lm) * LDK + quad * 8]);
#pragma unroll
            for (int s = 0; s < 4; ++s)
#pragma unroll
                for (int t = 0; t < 4; ++t)
                    acc[s][t] = __builtin_amdgcn_mfma_f32_16x16x32_bf16(af[s], bf[t], acc[s][t], 0, 0, 0);
            __syncthreads();
        }

        // epilogue: contract 2 i-values of this ct into lds_msg (2 phases, no atomics)
        const int il = ct * 2 + wn;     // i index within the block's 8
#pragma unroll
        for (int ph = 0; ph < 2; ++ph) {
            if (wn == ph) {
#pragma unroll
                for (int s = 0; s < 4; ++s) {
                    const int m = wm * 64 + s * 16 + quad * 4;
#pragma unroll
                    for (int t = 0; t < 4; ++t) {
                        const int o = t * 16 + lm;
#pragma unroll
                        for (int r = 0; r < 4; ++r)
                            lds_msg[(m + r) * 64 + o] += lds_xs[(m + r) * 8 + il] * acc[s][t][r];
                    }
                }
            }
            __syncthreads();
        }
    }

    // flush block's msg contribution
#pragma unroll
    for (int it = 0; it < 32; ++it) {
        int idx = it * 256 + tid;
        atomicAdd(&msg[e0 * 64 + idx], lds_msg[idx]);
    }
}

// ---------------------------------------------------------------------------
// 5. scatter-sum msg -> agg[dst], count edges per node
// ---------------------------------------------------------------------------
__global__ void scatter(const float* __restrict__ msg, const int* __restrict__ dst,
                        float* __restrict__ agg, float* __restrict__ cnt) {
    const int e = blockIdx.x * 4 + (threadIdx.x >> 6);
    const int o = threadIdx.x & 63;
    const int d = dst[e];
    atomicAdd(&agg[d * 64 + o], msg[e * 64 + o]);
    if (o == 0) atomicAdd(&cnt[d], 1.f);
}

// ---------------------------------------------------------------------------
// 6. x_next = relu(agg/cnt + x @ root + bias)
// ---------------------------------------------------------------------------
__global__ void combine(const float* __restrict__ agg, const float* __restrict__ cnt,
                        const float* __restrict__ xcur, const float* __restrict__ root,
                        const float* __restrict__ bias, float* __restrict__ xn) {
    const int n = blockIdx.x * 4 + (threadIdx.x >> 6);
    const int o = threadIdx.x & 63;
    float a = agg[n * 64 + o] / fmaxf(cnt[n], 1.f);
    float r = bias[o];
#pragma unroll
    for (int i = 0; i < 64; ++i) r += xcur[n * 64 + i] * root[i * 64 + o];
    xn[n * 64 + o] = fmaxf(a + r, 0.f);
}

// ---------------------------------------------------------------------------
// 7/8. global mean pool
// ---------------------------------------------------------------------------
__global__ void pool_accum(const float* __restrict__ x3, const int* __restrict__ batch,
                           float* __restrict__ pool, float* __restrict__ pcnt) {
    const int n = blockIdx.x * 4 + (threadIdx.x >> 6);
    const int o = threadIdx.x & 63;
    const int g = batch[n];
    atomicAdd(&pool[g * 64 + o], x3[n * 64 + o]);
    if (o == 0) atomicAdd(&pcnt[g], 1.f);
}

__global__ void pool_norm(const float* __restrict__ pool, const float* __restrict__ pcnt,
                          float* __restrict__ out) {
    const int idx = blockIdx.x * 256 + threadIdx.x;
    out[idx] = pool[idx] / fmaxf(pcnt[idx >> 6], 1.f);
}

// ---------------------------------------------------------------------------
extern "C" void kernel_launch(void* const* d_in, const int* in_sizes, int n_in,
                              void* d_out, int out_size, void* d_ws, size_t ws_size,
                              hipStream_t stream) {
    const float* x    = (const float*)d_in[0];
    const int*   ei   = (const int*)d_in[1];
    const float* ea   = (const float*)d_in[2];
    const int*   bat  = (const int*)d_in[3];
    const int* srcp = ei;
    const int* dstp = ei + EE;

    char* ws = (char*)d_ws;
    size_t off = 0;
    unsigned short* hB  = (unsigned short*)(ws + off); off += (size_t)EE * HD * 2;   // 128 MB
    unsigned short* w2t = (unsigned short*)(ws + off); off += (size_t)HD * HD * 2;   // 32 MB
    float* msg  = (float*)(ws + off); off += (size_t)EE * 64 * 4;                    // 4 MB
    float* agg  = (float*)(ws + off); off += (size_t)NN * 64 * 4;                    // 1 MB
    float* cnt  = (float*)(ws + off); off += (size_t)NN * 4;
    float* xb0  = (float*)(ws + off); off += (size_t)NN * 64 * 4;
    float* xb1  = (float*)(ws + off); off += (size_t)NN * 64 * 4;
    float* pool = (float*)(ws + off); off += (size_t)GG * 64 * 4;
    float* pcnt = (float*)(ws + off); off += (size_t)GG * 4;

    const float* xcur = x;
    float* xbufs[2] = {xb0, xb1};

    for (int l = 0; l < 3; ++l) {
        const float* w1   = (const float*)d_in[4 + 6 * l + 0];
        const float* b1   = (const float*)d_in[4 + 6 * l + 1];
        const float* w2   = (const float*)d_in[4 + 6 * l + 2];
        const float* b2   = (const float*)d_in[4 + 6 * l + 3];
        const float* root = (const float*)d_in[4 + 6 * l + 4];
        const float* bias = (const float*)d_in[4 + 6 * l + 5];

        wcast<<<dim3(HD / 64, HD / 64), 256, 0, stream>>>(w2, w2t);
        hker<<<dim3(HD / 256, EE / 16), 256, 0, stream>>>(ea, w1, b1, hB);
        msg_init<<<dim3(EE / 4), 256, 0, stream>>>(xcur, srcp, b2, msg);
        hipMemsetAsync(agg, 0, (size_t)NN * 64 * 4 + (size_t)NN * 4, stream); // agg+cnt contiguous
        gemm_msg<<<dim3(EE / BM, HD / 512), 256, 0, stream>>>(hB, w2t, xcur, srcp, msg);
        scatter<<<dim3(EE / 4), 256, 0, stream>>>(msg, dstp, agg, cnt);
        float* xn = xbufs[l & 1];
        combine<<<dim3(NN / 4), 256, 0, stream>>>(agg, cnt, xcur, root, bias, xn);
        xcur = xn;
    }
    hipMemsetAsync(pool, 0, (size_t)GG * 64 * 4 + (size_t)GG * 4, stream); // pool+pcnt contiguous
    pool_accum<<<dim3(NN / 4), 256, 0, stream>>>(xcur, bat, pool, pcnt);
    pool_norm<<<dim3(GG * 64 / 256), 256, 0, stream>>>(pool, pcnt, (float*)d_out);
}

// Round 2
// 2234.972 us; speedup vs baseline: 1.2736x; 1.2736x over previous
//
#include <hip/hip_runtime.h>
#include <hip/hip_bf16.h>

// Problem constants (fixed by reference)
#define NN 4096      // nodes
#define EE 16384     // edges
#define GG 128       // graphs
#define HH 64        // hidden / in_dim
#define EDIM 16      // edge_dim
#define HD 4096      // edge-MLP width = 64*64

typedef __attribute__((ext_vector_type(8))) short short8;
typedef __attribute__((ext_vector_type(4))) float float4v;

static __device__ inline unsigned short f2b(float f) {
    unsigned u = __float_as_uint(f);
    unsigned r = u + 0x7fff + ((u >> 16) & 1);   // RNE
    return (unsigned short)(r >> 16);
}

// ---------------------------------------------------------------------------
// 1. w2 [HD][HD] fp32  ->  w2t [n][k] bf16 (transposed), LDS-tiled
// ---------------------------------------------------------------------------
__global__ void wcast(const float* __restrict__ w2, unsigned short* __restrict__ w2t) {
    __shared__ float t[64 * 65];
    const int n0 = blockIdx.x * 64;
    const int k0 = blockIdx.y * 64;
    const int tid = threadIdx.x;
    const int cr = tid >> 6;   // 0..3
    const int cc = tid & 63;
#pragma unroll
    for (int it = 0; it < 16; ++it) {
        int kl = it * 4 + cr;
        t[kl * 65 + cc] = w2[(size_t)(k0 + kl) * HD + n0 + cc];
    }
    __syncthreads();
#pragma unroll
    for (int it = 0; it < 16; ++it) {
        int nl = it * 4 + cr;
        w2t[(size_t)(n0 + nl) * HD + k0 + cc] = f2b(t[cc * 65 + nl]);
    }
}

// ---------------------------------------------------------------------------
// 2. h = relu(ea @ w1 + b1) -> bf16 [EE][HD]
// ---------------------------------------------------------------------------
__global__ void hker(const float* __restrict__ ea, const float* __restrict__ w1,
                     const float* __restrict__ b1, unsigned short* __restrict__ hB) {
    __shared__ float sea[16 * 16];
    const int tid = threadIdx.x;
    const int j = blockIdx.x * 256 + tid;
    const int e0 = blockIdx.y * 16;
    float w[16];
#pragma unroll
    for (int k = 0; k < 16; ++k) w[k] = w1[k * HD + j];
    const float b = b1[j];
    sea[tid] = ea[e0 * EDIM + tid];
    __syncthreads();
#pragma unroll 4
    for (int el = 0; el < 16; ++el) {
        float a = b;
#pragma unroll
        for (int k = 0; k < 16; ++k) a += sea[el * 16 + k] * w[k];
        hB[(size_t)(e0 + el) * HD + j] = f2b(fmaxf(a, 0.f));
    }
}

// ---------------------------------------------------------------------------
// 3. msg[e,o] = sum_i x[src[e],i] * b2[i*64+o]   (fp32; also zero-inits msg)
// ---------------------------------------------------------------------------
__global__ void msg_init(const float* __restrict__ xcur, const int* __restrict__ src,
                         const float* __restrict__ b2, float* __restrict__ msg) {
    const int e = blockIdx.x * 4 + (threadIdx.x >> 6);
    const int o = threadIdx.x & 63;
    const int s = src[e];
    float a = 0.f;
#pragma unroll
    for (int i = 0; i < 64; ++i) a += xcur[s * 64 + i] * b2[i * 64 + o];
    msg[e * 64 + o] = a;
}

// ---------------------------------------------------------------------------
// 4. Fused GEMM+contract. Block = [128 edges x 256 cols] (= 4 i-values).
//    grid (EE/128, HD/256) = (128, 16); 4 waves 2x2, wave tile 64x128.
//    Staging via global_load_lds width=16 (no VGPR roundtrip, no LDS writes).
//    msg[e,o] += sum_i x_src[e,i] * D[e, i*64+o], accumulated in LDS, one
//    atomic flush per block.
// ---------------------------------------------------------------------------
#define BM 128
#define BN 256
#define BK 32

__global__ __launch_bounds__(256, 2)
void gemm_msg(const unsigned short* __restrict__ hB, const unsigned short* __restrict__ w2t,
              const float* __restrict__ xcur, const int* __restrict__ src,
              float* __restrict__ msg) {
    // unpadded rows: 32 bf16 = 64 B per row (required by global_load_lds)
    __shared__ __align__(16) unsigned short As[BM * BK];   //  8 KB
    __shared__ __align__(16) unsigned short Bs[BN * BK];   // 16 KB
    __shared__ float lds_msg[BM * 64];                     // 32 KB
    __shared__ float lds_xs[BM * 4];                       //  2 KB

    const int tid = threadIdx.x;
    const int e0 = blockIdx.x * BM;
    const int by = blockIdx.y;
    const int n0 = by * BN;

    // stage x[src[e], by*4 .. by*4+3]
#pragma unroll
    for (int it = 0; it < 2; ++it) {
        int idx = it * 256 + tid;       // 0..511
        int r = idx >> 2, ii = idx & 3;
        lds_xs[idx] = xcur[(size_t)src[e0 + r] * 64 + by * 4 + ii];
    }
#pragma unroll
    for (int it = 0; it < 32; ++it) lds_msg[it * 256 + tid] = 0.f;

    const int lane = tid & 63;
    const int wave = tid >> 6;
    const int quad = lane >> 4;
    const int lm = lane & 15;
    const int wm = wave >> 1;           // row half (0,1)
    const int wn = wave & 1;            // col half (0,1)

    // DMA source addressing: chunk c covers 16 rows x 64 B (1 KB);
    // lane l -> row c*16 + l/4, bytes (l%4)*16
    const int drow = lane >> 2;
    const int dcol = (lane & 3) * 8;    // in bf16 elems

    float4v acc[4][8];
#pragma unroll
    for (int s = 0; s < 4; ++s)
#pragma unroll
        for (int t = 0; t < 8; ++t) {
            acc[s][t][0] = 0.f; acc[s][t][1] = 0.f;
            acc[s][t][2] = 0.f; acc[s][t][3] = 0.f;
        }

    __syncthreads();   // lds_xs / lds_msg ready (As/Bs not yet touched)

    for (int ks = 0; ks < HD / BK; ++ks) {
        const int k0 = ks * BK;
        // 24 chunks total (A:0-7, B:8-23), 6 per wave
#pragma unroll
        for (int j = 0; j < 6; ++j) {
            const int c = wave * 6 + j;
            if (c < 8) {
                const unsigned short* g =
                    hB + (size_t)(e0 + c * 16 + drow) * HD + k0 + dcol;
                unsigned short* l = &As[c * 512 + lane * 8];
                __builtin_amdgcn_global_load_lds(
                    (const __attribute__((address_space(1))) unsigned int*)g,
                    (__attribute__((address_space(3))) unsigned int*)l, 16, 0, 0);
            } else {
                const int cb = c - 8;
                const unsigned short* g =
                    w2t + (size_t)(n0 + cb * 16 + drow) * HD + k0 + dcol;
                unsigned short* l = &Bs[cb * 512 + lane * 8];
                __builtin_amdgcn_global_load_lds(
                    (const __attribute__((address_space(1))) unsigned int*)g,
                    (__attribute__((address_space(3))) unsigned int*)l, 16, 0, 0);
            }
        }
        __syncthreads();   // barrier drains vmcnt -> DMA complete

        short8 af[4], bf[8];
#pragma unroll
        for (int s = 0; s < 4; ++s)
            af[s] = *(const short8*)(&As[(wm * 64 + s * 16 + lm) * BK + quad * 8]);
#pragma unroll
        for (int t = 0; t < 8; ++t)
            bf[t] = *(const short8*)(&Bs[(wn * 128 + t * 16 + lm) * BK + quad * 8]);
#pragma unroll
        for (int s = 0; s < 4; ++s)
#pragma unroll
            for (int t = 0; t < 8; ++t)
                acc[s][t] = __builtin_amdgcn_mfma_f32_16x16x32_bf16(af[s], bf[t], acc[s][t], 0, 0, 0);
        __syncthreads();   // reads done before next DMA overwrites
    }

    // epilogue: contract i into lds_msg; wn=0 holds i_loc 0,1; wn=1 holds 2,3.
    // 2 phases so the two wn-halves don't race on the same [m][o].
#pragma unroll
    for (int ph = 0; ph < 2; ++ph) {
        if (wn == ph) {
#pragma unroll
            for (int s = 0; s < 4; ++s) {
#pragma unroll
                for (int t = 0; t < 8; ++t) {
                    const int iloc = wn * 2 + (t >> 2);
                    const int o = (t & 3) * 16 + lm;
#pragma unroll
                    for (int r = 0; r < 4; ++r) {
                        const int m = wm * 64 + s * 16 + quad * 4 + r;
                        lds_msg[m * 64 + o] += lds_xs[m * 4 + iloc] * acc[s][t][r];
                    }
                }
            }
        }
        __syncthreads();
    }

    // flush block's msg contribution
#pragma unroll
    for (int it = 0; it < 32; ++it) {
        int idx = it * 256 + tid;
        atomicAdd(&msg[e0 * 64 + idx], lds_msg[idx]);
    }
}

// ---------------------------------------------------------------------------
// 5. scatter-sum msg -> agg[dst], count edges per node
// ---------------------------------------------------------------------------
__global__ void scatter(const float* __restrict__ msg, const int* __restrict__ dst,
                        float* __restrict__ agg, float* __restrict__ cnt) {
    const int e = blockIdx.x * 4 + (threadIdx.x >> 6);
    const int o = threadIdx.x & 63;
    const int d = dst[e];
    atomicAdd(&agg[d * 64 + o], msg[e * 64 + o]);
    if (o == 0) atomicAdd(&cnt[d], 1.f);
}

// ---------------------------------------------------------------------------
// 6. x_next = relu(agg/cnt + x @ root + bias)
// ---------------------------------------------------------------------------
__global__ void combine(const float* __restrict__ agg, const float* __restrict__ cnt,
                        const float* __restrict__ xcur, const float* __restrict__ root,
                        const float* __restrict__ bias, float* __restrict__ xn) {
    const int n = blockIdx.x * 4 + (threadIdx.x >> 6);
    const int o = threadIdx.x & 63;
    float a = agg[n * 64 + o] / fmaxf(cnt[n], 1.f);
    float r = bias[o];
#pragma unroll
    for (int i = 0; i < 64; ++i) r += xcur[n * 64 + i] * root[i * 64 + o];
    xn[n * 64 + o] = fmaxf(a + r, 0.f);
}

// ---------------------------------------------------------------------------
// 7/8. global mean pool
// ---------------------------------------------------------------------------
__global__ void pool_accum(const float* __restrict__ x3, const int* __restrict__ batch,
                           float* __restrict__ pool, float* __restrict__ pcnt) {
    const int n = blockIdx.x * 4 + (threadIdx.x >> 6);
    const int o = threadIdx.x & 63;
    const int g = batch[n];
    atomicAdd(&pool[g * 64 + o], x3[n * 64 + o]);
    if (o == 0) atomicAdd(&pcnt[g], 1.f);
}

__global__ void pool_norm(const float* __restrict__ pool, const float* __restrict__ pcnt,
                          float* __restrict__ out) {
    const int idx = blockIdx.x * 256 + threadIdx.x;
    out[idx] = pool[idx] / fmaxf(pcnt[idx >> 6], 1.f);
}

// ---------------------------------------------------------------------------
extern "C" void kernel_launch(void* const* d_in, const int* in_sizes, int n_in,
                              void* d_out, int out_size, void* d_ws, size_t ws_size,
                              hipStream_t stream) {
    const float* x    = (const float*)d_in[0];
    const int*   ei   = (const int*)d_in[1];
    const float* ea   = (const float*)d_in[2];
    const int*   bat  = (const int*)d_in[3];
    const int* srcp = ei;
    const int* dstp = ei + EE;

    char* ws = (char*)d_ws;
    size_t off = 0;
    unsigned short* hB  = (unsigned short*)(ws + off); off += (size_t)EE * HD * 2;   // 128 MB
    unsigned short* w2t = (unsigned short*)(ws + off); off += (size_t)HD * HD * 2;   // 32 MB
    float* msg  = (float*)(ws + off); off += (size_t)EE * 64 * 4;                    // 4 MB
    float* agg  = (float*)(ws + off); off += (size_t)NN * 64 * 4;                    // 1 MB
    float* cnt  = (float*)(ws + off); off += (size_t)NN * 4;
    float* xb0  = (float*)(ws + off); off += (size_t)NN * 64 * 4;
    float* xb1  = (float*)(ws + off); off += (size_t)NN * 64 * 4;
    float* pool = (float*)(ws + off); off += (size_t)GG * 64 * 4;
    float* pcnt = (float*)(ws + off); off += (size_t)GG * 4;

    const float* xcur = x;
    float* xbufs[2] = {xb0, xb1};

    for (int l = 0; l < 3; ++l) {
        const float* w1   = (const float*)d_in[4 + 6 * l + 0];
        const float* b1   = (const float*)d_in[4 + 6 * l + 1];
        const float* w2   = (const float*)d_in[4 + 6 * l + 2];
        const float* b2   = (const float*)d_in[4 + 6 * l + 3];
        const float* root = (const float*)d_in[4 + 6 * l + 4];
        const float* bias = (const float*)d_in[4 + 6 * l + 5];

        wcast<<<dim3(HD / 64, HD / 64), 256, 0, stream>>>(w2, w2t);
        hker<<<dim3(HD / 256, EE / 16), 256, 0, stream>>>(ea, w1, b1, hB);
        msg_init<<<dim3(EE / 4), 256, 0, stream>>>(xcur, srcp, b2, msg);
        hipMemsetAsync(agg, 0, (size_t)NN * 64 * 4 + (size_t)NN * 4, stream); // agg+cnt contiguous
        gemm_msg<<<dim3(EE / BM, HD / BN), 256, 0, stream>>>(hB, w2t, xcur, srcp, msg);
        scatter<<<dim3(EE / 4), 256, 0, stream>>>(msg, dstp, agg, cnt);
        float* xn = xbufs[l & 1];
        combine<<<dim3(NN / 4), 256, 0, stream>>>(agg, cnt, xcur, root, bias, xn);
        xcur = xn;
    }
    hipMemsetAsync(pool, 0, (size_t)GG * 64 * 4 + (size_t)GG * 4, stream); // pool+pcnt contiguous
    pool_accum<<<dim3(NN / 4), 256, 0, stream>>>(xcur, bat, pool, pcnt);
    pool_norm<<<dim3(GG * 64 / 256), 256, 0, stream>>>(pool, pcnt, (float*)d_out);
}